// Round 8
// baseline (42.118 us; speedup 1.0000x reference)
//
#include <hip/hip_runtime.h>
#include <stdint.h>

#define BB 512
#define TT 500
#define KK 64
#define DD 64
#define NTH 256
#define NW 4             // waves per block
#define TWS 125          // TT / NW

// One 256-thread block per batch element b; 8 blocks/CU so streaming and
// compute phases of different blocks interleave. Zero global scratch.
// chain dtype (bf16 vs f32) sniffed per-wave from its first 256 B:
//   f32 one-hot row = 64 words, exactly 1 nonzero; bf16 = rows 0,1 -> 2 nonzero.
__launch_bounds__(NTH, 8)
__global__ void bkt_fused(const int* __restrict__ corr,
                          const uint32_t* __restrict__ chainw,
                          const float* __restrict__ embd,
                          const float* __restrict__ Wf,
                          const float* __restrict__ bias,
                          float2* __restrict__ out) {
    __shared__ uint8_t corr_s[TT];
    __shared__ uint8_t evs[TT];
    __shared__ float g0s[KK], g1s[KK], t10s[KK], t11s[KK], p1s[KK];
    __shared__ int cnt[NW][KK];
    __shared__ int startw[NW][KK];
    __shared__ int segs[KK], sege[KK];
    __shared__ uint16_t lst[TT];
    __shared__ __align__(16) float out_s[TT][2];

    const int b = blockIdx.x;
    const int tid = threadIdx.x;
    const int w = tid >> 6, lane = tid & 63;

    // ---------- per-wave dtype sniff (ballot broadcasts; no barrier) ----------
    uint32_t sv = chainw[lane];
    unsigned long long sm = __ballot(sv != 0u);
    const bool isb = (__popcll(sm) >= 2);

    // ---------- corr staging (independent) ----------
    if (tid < TT) corr_s[tid] = (uint8_t)corr[b * TT + tid];
    if (tid + NTH < TT) corr_s[tid + NTH] = (uint8_t)corr[b * TT + tid + NTH];

    // ---------- phase B: one-hot detect over chain[b] (16-32 indep loads/thread) ----------
    if (isb) {
        const uint4* cb = (const uint4*)(chainw + (size_t)b * (TT * 32));   // 128 B rows
#pragma unroll
        for (int it = 0; it < 16; ++it) {
            int f = it * NTH + tid;                 // flat uint4 index, 0..3999
            if (f < TT * 8) {
                uint4 v = cb[f];
                int row = f >> 3, u = f & 7;
                uint32_t wd[4] = {v.x, v.y, v.z, v.w};
                int j = -1;
#pragma unroll
                for (int q = 0; q < 4; ++q) {
                    if ((wd[q] & 0xFFFFu) == 0x3F80u) j = q * 2;
                    if ((wd[q] >> 16)     == 0x3F80u) j = q * 2 + 1;
                }
                if (j >= 0) evs[row] = (uint8_t)(u * 8 + j);
            }
        }
    } else {
        const uint4* cb = (const uint4*)(chainw + (size_t)b * (TT * 64));   // 256 B rows
#pragma unroll
        for (int it = 0; it < 32; ++it) {
            int f = it * NTH + tid;                 // flat uint4 index, 0..7999
            if (f < TT * 16) {
                uint4 v = cb[f];
                int row = f >> 4, u = f & 15;
                int j = (v.x == 0x3F800000u) ? 0 : (v.y == 0x3F800000u) ? 1
                      : (v.z == 0x3F800000u) ? 2 : (v.w == 0x3F800000u) ? 3 : -1;
                if (j >= 0) evs[row] = (uint8_t)(u * 4 + j);
            }
        }
    }

    // ---------- params: lanes 0..63 (wave 0), weights straight from L2 ----------
    if (tid < KK) {
        const int k = tid;
        float l0 = bias[0], l1 = bias[1], l2 = bias[2], l3 = bias[3], l4 = bias[4];
        const float4* er = (const float4*)(embd + k * DD);
        const float4* w0 = (const float4*)(Wf + 0 * DD);
        const float4* w1 = (const float4*)(Wf + 1 * DD);
        const float4* w2 = (const float4*)(Wf + 2 * DD);
        const float4* w3 = (const float4*)(Wf + 3 * DD);
        const float4* w4 = (const float4*)(Wf + 4 * DD);
#pragma unroll 4
        for (int d4 = 0; d4 < DD / 4; ++d4) {
            float4 e = er[d4];
            float4 a;
            a = w0[d4]; l0 = fmaf(e.x,a.x,fmaf(e.y,a.y,fmaf(e.z,a.z,fmaf(e.w,a.w,l0))));
            a = w1[d4]; l1 = fmaf(e.x,a.x,fmaf(e.y,a.y,fmaf(e.z,a.z,fmaf(e.w,a.w,l1))));
            a = w2[d4]; l2 = fmaf(e.x,a.x,fmaf(e.y,a.y,fmaf(e.z,a.z,fmaf(e.w,a.w,l2))));
            a = w3[d4]; l3 = fmaf(e.x,a.x,fmaf(e.y,a.y,fmaf(e.z,a.z,fmaf(e.w,a.w,l3))));
            a = w4[d4]; l4 = fmaf(e.x,a.x,fmaf(e.y,a.y,fmaf(e.z,a.z,fmaf(e.w,a.w,l4))));
        }
        auto sig = [](float x) { return 1.0f / (1.0f + __expf(-x)); };
        t10s[k] = sig( 2.f * l0);   // p(s'=1 | s=0)
        t11s[k] = sig(-2.f * l1);   // p(s'=1 | s=1)
        g0s[k]  = sig( 2.f * l2);   // p(y=1 | s=0)
        g1s[k]  = sig(-2.f * l3);   // p(y=1 | s=1)
        p1s[k]  = sig( 2.f * l4);   // p(s=1) initial
    }
    __syncthreads();   // evs, corr_s, params all ready

    // ---------- phase C: stable counting sort by k (4 waves x 125-t slices) ----------
    const int t0 = w * TWS;
    int c = 0;
    for (int t = t0; t < t0 + TWS; ++t) c += (evs[t] == lane);
    cnt[w][lane] = c;
    __syncthreads();

    if (w == 0) {
        int c0 = cnt[0][lane], c1 = cnt[1][lane], c2 = cnt[2][lane], c3 = cnt[3][lane];
        int tot = c0 + c1 + c2 + c3;
        int x = tot;
#pragma unroll
        for (int d = 1; d < 64; d <<= 1) {
            int o = __shfl_up(x, d);
            if (lane >= d) x += o;
        }
        int excl = x - tot;
        segs[lane] = excl;
        sege[lane] = excl + tot;
        int s = excl;
        startw[0][lane] = s; s += c0;
        startw[1][lane] = s; s += c1;
        startw[2][lane] = s; s += c2;
        startw[3][lane] = s;
    }
    __syncthreads();

    int ptr = startw[w][lane];
    for (int t = t0; t < t0 + TWS; ++t)
        if (evs[t] == lane) lst[ptr++] = (uint16_t)t;
    __syncthreads();

    // ---------- phase D: per-k scalar HMM filter (wave 0, lane = k) ----------
    if (w == 0) {
        const int k = lane;
        float g0 = g0s[k], g1 = g1s[k], t10 = t10s[k], t11 = t11s[k];
        float dg = g1 - g0, dt = t11 - t10, g1c = 1.f - g1;
        float p1 = p1s[k];
        const int e_ = sege[k];
        for (int i = segs[k]; i < e_; ++i) {
            int t = lst[i];
            int y = corr_s[t];
            float pe1 = fmaf(p1, dg, g0);
            float pe0 = 1.f - pe1;
            out_s[t][0] = __logf(pe0);
            out_s[t][1] = __logf(pe1);
            float gy  = y ? g1  : g1c;
            float pyy = y ? pe1 : pe0;
            float w1 = p1 * gy / pyy;
            p1 = fmaf(w1, dt, t10);
        }
    }
    __syncthreads();

    // ---------- phase E: coalesced store (500 float2 = 4000 B = 250 uint4) ----------
    uint4* dst = (uint4*)(out + (size_t)b * TT);
    const uint4* src = (const uint4*)out_s;
    if (tid < 250) dst[tid] = src[tid];
}

extern "C" void kernel_launch(void* const* d_in, const int* in_sizes, int n_in,
                              void* d_out, int out_size, void* d_ws, size_t ws_size,
                              hipStream_t stream) {
    // Identify inputs by flat element count (robust to ordering).
    const void* p_corr = nullptr, *p_chain = nullptr, *p_embd = nullptr,
              * p_Wf = nullptr, *p_bias = nullptr;
    for (int i = 0; i < n_in; ++i) {
        switch (in_sizes[i]) {
            case BB * TT:        p_corr  = d_in[i]; break;   // 256000
            case BB * TT * KK:   p_chain = d_in[i]; break;   // 16384000
            case KK * DD:        p_embd  = d_in[i]; break;   // 4096
            case 5 * DD:         p_Wf    = d_in[i]; break;   // 320
            case 5:              p_bias  = d_in[i]; break;
            default: break;
        }
    }
    if (!p_corr)  p_corr  = d_in[0];
    if (!p_chain) p_chain = d_in[1];
    if (!p_embd)  p_embd  = d_in[2];
    if (!p_Wf)    p_Wf    = d_in[3];
    if (!p_bias)  p_bias  = d_in[4];
    (void)d_ws; (void)ws_size; (void)out_size;

    bkt_fused<<<BB, NTH, 0, stream>>>((const int*)p_corr,
                                      (const uint32_t*)p_chain,
                                      (const float*)p_embd,
                                      (const float*)p_Wf,
                                      (const float*)p_bias,
                                      (float2*)d_out);
}

// Round 9
// 38.473 us; speedup vs baseline: 1.0947x; 1.0947x over previous
//
#include <hip/hip_runtime.h>
#include <stdint.h>

#define BB 512
#define TT 500
#define KK 64
#define DD 64
#define NROWS (BB*TT)

// ---------------- kernel A: pure streaming one-hot detect ----------------
// Grid-stride over the whole chain buffer; ev[row] = k (6 bits).
// chain dtype (bf16 vs f32) sniffed per-wave from its first 256 B:
//   f32 one-hot row = 64 words, exactly 1 nonzero; bf16 = rows 0,1 -> 2 nonzero.
__launch_bounds__(256, 8)
__global__ void ev_stream(const uint32_t* __restrict__ chainw,
                          uint8_t* __restrict__ ev) {
    const int lane = threadIdx.x & 63;
    uint32_t sv = chainw[lane];
    unsigned long long sm = __ballot(sv != 0u);
    const bool isb = (__popcll(sm) >= 2);

    const int gid = blockIdx.x * blockDim.x + threadIdx.x;
    const int gsz = gridDim.x * blockDim.x;
    const uint4* cb = (const uint4*)chainw;

    if (isb) {
        const int N4 = NROWS * 8;                  // 128 B rows: 8 uint4 each
        for (int f = gid; f < N4; f += gsz) {
            uint4 v = cb[f];
            uint32_t wd[4] = {v.x, v.y, v.z, v.w};
            int j = -1;
#pragma unroll
            for (int q = 0; q < 4; ++q) {
                if ((wd[q] & 0xFFFFu) == 0x3F80u) j = q * 2;
                if ((wd[q] >> 16)     == 0x3F80u) j = q * 2 + 1;
            }
            if (j >= 0) ev[f >> 3] = (uint8_t)((f & 7) * 8 + j);
        }
    } else {
        const int N4 = NROWS * 16;                 // 256 B rows: 16 uint4 each
        for (int f = gid; f < N4; f += gsz) {
            uint4 v = cb[f];
            int j = (v.x == 0x3F800000u) ? 0 : (v.y == 0x3F800000u) ? 1
                  : (v.z == 0x3F800000u) ? 2 : (v.w == 0x3F800000u) ? 3 : -1;
            if (j >= 0) ev[f >> 4] = (uint8_t)((f & 15) * 4 + j);
        }
    }
}

// ---------------- kernel B: per-b sort + scalar HMM filter ----------------
__launch_bounds__(256, 8)
__global__ void bkt_filter(const uint8_t* __restrict__ ev,
                           const int* __restrict__ corr,
                           const float* __restrict__ embd,
                           const float* __restrict__ Wf,
                           const float* __restrict__ bias,
                           float2* __restrict__ out) {
    __shared__ uint8_t evs[TT];
    __shared__ uint8_t corr_s[TT];
    __shared__ float g0s[KK], g1s[KK], t10s[KK], t11s[KK], p1s[KK];
    __shared__ int cnt[4][KK];
    __shared__ int startw[4][KK];
    __shared__ int segs[KK], sege[KK];
    __shared__ uint16_t lst[TT];
    __shared__ __align__(16) float out_s[TT][2];

    const int b = blockIdx.x;
    const int tid = threadIdx.x;
    const int w = tid >> 6, lane = tid & 63;

    // ---------- stage ev row (500 B) + corr (independent loads) ----------
    if (tid < TT/4) ((uint32_t*)evs)[tid] = ((const uint32_t*)(ev + (size_t)b*TT))[tid];
    if (tid == 255) ((uint32_t*)evs)[124] = ((const uint32_t*)(ev + (size_t)b*TT))[124];
    if (tid < TT) corr_s[tid] = (uint8_t)corr[b*TT + tid];
    if (tid + 256 < TT) corr_s[tid + 256] = (uint8_t)corr[b*TT + tid + 256];

    // ---------- params: lanes 0..63 (wave 0), weights from L2 ----------
    if (tid < KK) {
        const int k = tid;
        float l0 = bias[0], l1 = bias[1], l2 = bias[2], l3 = bias[3], l4 = bias[4];
        const float4* er = (const float4*)(embd + k * DD);
        const float4* w0 = (const float4*)(Wf + 0 * DD);
        const float4* w1 = (const float4*)(Wf + 1 * DD);
        const float4* w2 = (const float4*)(Wf + 2 * DD);
        const float4* w3 = (const float4*)(Wf + 3 * DD);
        const float4* w4 = (const float4*)(Wf + 4 * DD);
#pragma unroll 4
        for (int d4 = 0; d4 < DD / 4; ++d4) {
            float4 e = er[d4];
            float4 a;
            a = w0[d4]; l0 = fmaf(e.x,a.x,fmaf(e.y,a.y,fmaf(e.z,a.z,fmaf(e.w,a.w,l0))));
            a = w1[d4]; l1 = fmaf(e.x,a.x,fmaf(e.y,a.y,fmaf(e.z,a.z,fmaf(e.w,a.w,l1))));
            a = w2[d4]; l2 = fmaf(e.x,a.x,fmaf(e.y,a.y,fmaf(e.z,a.z,fmaf(e.w,a.w,l2))));
            a = w3[d4]; l3 = fmaf(e.x,a.x,fmaf(e.y,a.y,fmaf(e.z,a.z,fmaf(e.w,a.w,l3))));
            a = w4[d4]; l4 = fmaf(e.x,a.x,fmaf(e.y,a.y,fmaf(e.z,a.z,fmaf(e.w,a.w,l4))));
        }
        auto sig = [](float x) { return 1.0f / (1.0f + __expf(-x)); };
        t10s[k] = sig( 2.f * l0);   // p(s'=1 | s=0)
        t11s[k] = sig(-2.f * l1);   // p(s'=1 | s=1)
        g0s[k]  = sig( 2.f * l2);   // p(y=1 | s=0)
        g1s[k]  = sig(-2.f * l3);   // p(y=1 | s=1)
        p1s[k]  = sig( 2.f * l4);   // p(s=1) initial
    }
    __syncthreads();

    // ---------- stable counting sort by k (4 waves x 125-t slices) ----------
    const int TWS = TT / 4;
    const int t0 = w * TWS;
    int c = 0;
    for (int t = t0; t < t0 + TWS; ++t) c += (evs[t] == lane);
    cnt[w][lane] = c;
    __syncthreads();

    if (w == 0) {
        int c0 = cnt[0][lane], c1 = cnt[1][lane], c2 = cnt[2][lane], c3 = cnt[3][lane];
        int tot = c0 + c1 + c2 + c3;
        int x = tot;
#pragma unroll
        for (int d = 1; d < 64; d <<= 1) {
            int o = __shfl_up(x, d);
            if (lane >= d) x += o;
        }
        int excl = x - tot;
        segs[lane] = excl;
        sege[lane] = excl + tot;
        int s = excl;
        startw[0][lane] = s; s += c0;
        startw[1][lane] = s; s += c1;
        startw[2][lane] = s; s += c2;
        startw[3][lane] = s;
    }
    __syncthreads();

    int ptr = startw[w][lane];
    for (int t = t0; t < t0 + TWS; ++t)
        if (evs[t] == lane) lst[ptr++] = (uint16_t)t;
    __syncthreads();

    // ---------- per-k scalar HMM filter (wave 0, lane = k) ----------
    if (w == 0) {
        const int k = lane;
        float g0 = g0s[k], g1 = g1s[k], t10 = t10s[k], t11 = t11s[k];
        float dg = g1 - g0, dt = t11 - t10, g1c = 1.f - g1;
        float p1 = p1s[k];
        const int e_ = sege[k];
        for (int i = segs[k]; i < e_; ++i) {
            int t = lst[i];
            int y = corr_s[t];
            float pe1 = fmaf(p1, dg, g0);
            float pe0 = 1.f - pe1;
            out_s[t][0] = __logf(pe0);
            out_s[t][1] = __logf(pe1);
            float gy  = y ? g1  : g1c;
            float pyy = y ? pe1 : pe0;
            float w1 = p1 * gy / pyy;
            p1 = fmaf(w1, dt, t10);
        }
    }
    __syncthreads();

    // ---------- coalesced store (500 float2 = 4000 B = 250 uint4) ----------
    uint4* dst = (uint4*)(out + (size_t)b * TT);
    const uint4* src = (const uint4*)out_s;
    if (tid < 250) dst[tid] = src[tid];
}

extern "C" void kernel_launch(void* const* d_in, const int* in_sizes, int n_in,
                              void* d_out, int out_size, void* d_ws, size_t ws_size,
                              hipStream_t stream) {
    // Identify inputs by flat element count (robust to ordering).
    const void* p_corr = nullptr, *p_chain = nullptr, *p_embd = nullptr,
              * p_Wf = nullptr, *p_bias = nullptr;
    for (int i = 0; i < n_in; ++i) {
        switch (in_sizes[i]) {
            case BB * TT:        p_corr  = d_in[i]; break;   // 256000
            case BB * TT * KK:   p_chain = d_in[i]; break;   // 16384000
            case KK * DD:        p_embd  = d_in[i]; break;   // 4096
            case 5 * DD:         p_Wf    = d_in[i]; break;   // 320
            case 5:              p_bias  = d_in[i]; break;
            default: break;
        }
    }
    if (!p_corr)  p_corr  = d_in[0];
    if (!p_chain) p_chain = d_in[1];
    if (!p_embd)  p_embd  = d_in[2];
    if (!p_Wf)    p_Wf    = d_in[3];
    if (!p_bias)  p_bias  = d_in[4];
    (void)out_size;

    uint8_t* ev = (uint8_t*)d_ws;                  // 256 KB scratch (ws is ~256 MB)

    ev_stream<<<2048, 256, 0, stream>>>((const uint32_t*)p_chain, ev);
    bkt_filter<<<BB, 256, 0, stream>>>(ev,
                                       (const int*)p_corr,
                                       (const float*)p_embd,
                                       (const float*)p_Wf,
                                       (const float*)p_bias,
                                       (float2*)d_out);
}